// Round 15
// baseline (293.064 us; speedup 1.0000x reference)
//
#include <hip/hip_runtime.h>
#include <hip/hip_bf16.h>

#define B_  2
#define S_  2048
#define D_  1024
#define H_  16
#define DH_ 64

typedef __attribute__((ext_vector_type(8))) short bf16x8;
typedef __attribute__((ext_vector_type(4))) float f32x4;

__device__ __forceinline__ short f2bf(float f) {
  unsigned int u; __builtin_memcpy(&u, &f, 4);
  u = (u + 0x7FFFu + ((u >> 16) & 1u)) >> 16;
  return (short)u;
}
// packed f32x2 -> bf16x2 (RNE), lo = first arg
__device__ __forceinline__ unsigned cvtpk(float a, float b) {
  unsigned r;
  asm("v_cvt_pk_bf16_f32 %0, %1, %2" : "=v"(r) : "v"(a), "v"(b));
  return r;
}

#define GLOAD_LDS16(gp, lp) \
  __builtin_amdgcn_global_load_lds((const __attribute__((address_space(1))) void*)(gp), \
                                   (__attribute__((address_space(3))) void*)(lp), 16, 0, 0)

#define MFMA16(a, b, c) __builtin_amdgcn_mfma_f32_16x16x32_bf16(a, b, c, 0, 0, 0)

// lgkm-only barrier: LDS writes visible, in-flight global loads NOT drained.
#define RAW_BARRIER() do {                                   \
    asm volatile("s_waitcnt lgkmcnt(0)" ::: "memory");       \
    __builtin_amdgcn_s_barrier();                            \
    asm volatile("" ::: "memory");                           \
  } while (0)

union U8 { unsigned u[4]; bf16x8 v; };

// ---------------- f32 -> bf16 convert (x) + RoPE table (fused) ----------------
__global__ __launch_bounds__(256) void k_cvt_table(const float* __restrict__ in,
                                                   short* __restrict__ out,
                                                   float* __restrict__ cosT,
                                                   float* __restrict__ sinT) {
  int bid = blockIdx.x;
  if (bid < 4096) {
    int i = bid * 256 + threadIdx.x;
    float4 v = ((const float4*)in)[i];
    short4 o; o.x = f2bf(v.x); o.y = f2bf(v.y); o.z = f2bf(v.z); o.w = f2bf(v.w);
    *(short4*)(out + (size_t)i * 4) = o;
  } else {
    int i = (bid - 4096) * 256 + threadIdx.x;
    int s = i >> 5, d = i & 31;
    float invf = exp2f(-(float)d * (13.287712379549449f / 32.0f)); // 10000^(-d/32)
    float ang = (float)s * invf;
    cosT[i] = cosf(ang);
    sinT[i] = sinf(ang);
  }
}

// ---------------- 4 weights (f32 [K][N]) -> Wt (bf16 [N][K]), one launch ----------------
__global__ __launch_bounds__(256) void k_transpose4(const float* __restrict__ W0,
                                                    const float* __restrict__ W1,
                                                    const float* __restrict__ W2,
                                                    const float* __restrict__ W3,
                                                    short* __restrict__ WtBase) {
  __shared__ float tile[32][33];
  const float* W = (blockIdx.z == 0) ? W0 : (blockIdx.z == 1) ? W1 :
                   (blockIdx.z == 2) ? W2 : W3;
  short* Wt = WtBase + (size_t)blockIdx.z * D_ * D_;
  int tx = threadIdx.x, ty = threadIdx.y;
  int bx = blockIdx.x * 32, by = blockIdx.y * 32;
  #pragma unroll
  for (int i = 0; i < 32; i += 8)
    tile[ty + i][tx] = W[(size_t)(by + ty + i) * D_ + bx + tx];
  __syncthreads();
  #pragma unroll
  for (int i = 0; i < 32; i += 8)
    Wt[(size_t)(bx + ty + i) * D_ + by + tx] = f2bf(tile[tx][ty + i]);
}

// ---------------- fused QKV GEMM + bias + RoPE epilogue (XCD-swizzled grid) ----------------
__global__ __launch_bounds__(256) void k_gemm_qkv(const short* __restrict__ A,
                                                  const short* __restrict__ Bt,
                                                  const float* __restrict__ bq,
                                                  const float* __restrict__ bk,
                                                  const float* __restrict__ bv,
                                                  const float* __restrict__ cosT,
                                                  const float* __restrict__ sinT,
                                                  short* __restrict__ qb,
                                                  short* __restrict__ kb,
                                                  short* __restrict__ vb) {
  const int K = 1024;
  __shared__ __align__(16) short lA[128 * 32];
  __shared__ __align__(16) short lB[128 * 32];
  const int fid = blockIdx.y * 24 + blockIdx.x;
  const int swz = (fid & 7) * 96 + (fid >> 3);
  const int bxs = swz % 24, bys = swz / 24;
  const int tid = threadIdx.x;
  const int wid = tid >> 6, lane = tid & 63;
  const int brow = bys * 128, bcol = bxs * 128;
  const int wr = wid >> 1, wc = wid & 1;
  const int g = lane >> 4, c15 = lane & 15;
  const int sr = lane >> 2, scol = (lane & 3) * 8;
  f32x4 acc[4][4] = {};

  for (int kt = 0; kt < K; kt += 32) {
    __syncthreads();
    #pragma unroll
    for (int ch = 0; ch < 2; ++ch) {
      const short* ga = A + (size_t)(brow + ch * 64 + wid * 16 + sr) * K + kt + scol;
      const short* gb = Bt + (size_t)(bcol + ch * 64 + wid * 16 + sr) * K + kt + scol;
      GLOAD_LDS16(ga, &lA[(ch * 64 + wid * 16) * 32]);
      GLOAD_LDS16(gb, &lB[(ch * 64 + wid * 16) * 32]);
    }
    __syncthreads();
    bf16x8 af[4], bfr[4];
    #pragma unroll
    for (int mi = 0; mi < 4; ++mi)
      af[mi] = *(const bf16x8*)&lA[(wr * 64 + mi * 16 + c15) * 32 + g * 8];
    #pragma unroll
    for (int ni = 0; ni < 4; ++ni)
      bfr[ni] = *(const bf16x8*)&lB[(wc * 64 + ni * 16 + c15) * 32 + g * 8];
    #pragma unroll
    for (int mi = 0; mi < 4; ++mi)
      #pragma unroll
      for (int ni = 0; ni < 4; ++ni)
        acc[mi][ni] = MFMA16(af[mi], bfr[ni], acc[mi][ni]);
  }

  const int seg = bcol >> 10;                       // 0=q 1=k 2=v
  const float* bp = (seg == 0) ? bq : (seg == 1) ? bk : bv;
  short* dst = (seg == 0) ? qb : (seg == 1) ? kb : vb;
  const float alpha = (seg == 0) ? 0.18033688f : 1.0f;  // (1/8)*log2(e)
  const bool rope = (seg < 2);
  #pragma unroll
  for (int mi = 0; mi < 4; ++mi) {
    #pragma unroll
    for (int ni = 0; ni < 2; ++ni) {
      int col  = bcol + wc * 64 + ni * 16 + c15;
      int lcol = col & 1023;
      int d    = col & 63;
      float b1 = bp[lcol], b2 = bp[lcol + 32];
      #pragma unroll
      for (int r = 0; r < 4; ++r) {
        int row = brow + wr * 64 + mi * 16 + g * 4 + r;
        float x1 = (acc[mi][ni][r]     + b1) * alpha;
        float x2 = (acc[mi][ni + 2][r] + b2) * alpha;
        float o1 = x1, o2 = x2;
        if (rope) {
          int s = row & (S_ - 1);
          float co = cosT[s * 32 + d], si = sinT[s * 32 + d];
          o1 = x1 * co - x2 * si;
          o2 = x1 * si + x2 * co;
        }
        dst[(size_t)row * 1024 + lcol]      = f2bf(o1);
        dst[(size_t)row * 1024 + lcol + 32] = f2bf(o2);
      }
    }
  }
}

// ---------------- bf16 GEMM (Wo): C = A*Bt^T + bias(col), f32 out ----------------
__global__ __launch_bounds__(256) void k_gemm(const short* __restrict__ A,
                                              const short* __restrict__ Bt,
                                              const float* __restrict__ bias,
                                              float* __restrict__ out,
                                              int M, int N, int K) {
  __shared__ __align__(16) short lA[128 * 32];
  __shared__ __align__(16) short lB[128 * 32];
  const int fid = blockIdx.y * 8 + blockIdx.x;
  const int swz = (fid & 7) * 32 + (fid >> 3);
  const int bxs = swz % 8, bys = swz / 8;
  const int tid = threadIdx.x;
  const int wid = tid >> 6, lane = tid & 63;
  const int brow = bys * 128, bcol = bxs * 128;
  const int wr = wid >> 1, wc = wid & 1;
  const int g = lane >> 4, c15 = lane & 15;
  const int sr = lane >> 2, scol = (lane & 3) * 8;
  f32x4 acc[4][4] = {};

  for (int kt = 0; kt < K; kt += 32) {
    __syncthreads();
    #pragma unroll
    for (int ch = 0; ch < 2; ++ch) {
      const short* ga = A + (size_t)(brow + ch * 64 + wid * 16 + sr) * K + kt + scol;
      const short* gb = Bt + (size_t)(bcol + ch * 64 + wid * 16 + sr) * K + kt + scol;
      GLOAD_LDS16(ga, &lA[(ch * 64 + wid * 16) * 32]);
      GLOAD_LDS16(gb, &lB[(ch * 64 + wid * 16) * 32]);
    }
    __syncthreads();
    bf16x8 af[4], bfr[4];
    #pragma unroll
    for (int mi = 0; mi < 4; ++mi)
      af[mi] = *(const bf16x8*)&lA[(wr * 64 + mi * 16 + c15) * 32 + g * 8];
    #pragma unroll
    for (int ni = 0; ni < 4; ++ni)
      bfr[ni] = *(const bf16x8*)&lB[(wc * 64 + ni * 16 + c15) * 32 + g * 8];
    #pragma unroll
    for (int mi = 0; mi < 4; ++mi)
      #pragma unroll
      for (int ni = 0; ni < 4; ++ni)
        acc[mi][ni] = MFMA16(af[mi], bfr[ni], acc[mi][ni]);
  }

  #pragma unroll
  for (int mi = 0; mi < 4; ++mi) {
    #pragma unroll
    for (int ni = 0; ni < 4; ++ni) {
      int col = bcol + wc * 64 + ni * 16 + c15;
      float bv = bias[col];
      #pragma unroll
      for (int r = 0; r < 4; ++r) {
        int row = brow + wr * 64 + mi * 16 + g * 4 + r;
        out[(size_t)row * N + col] = acc[mi][ni][r] + bv;
      }
    }
  }
}

// ---- flash helpers (validated R5/R7 layouts) ----
__device__ __forceinline__ void softmax_g(f32x4 (&s)[4], float& m, float& l,
                                          f32x4 (&o)[4], int g) {
  float pm = -1e30f;
  #pragma unroll
  for (int n = 0; n < 4; ++n)
    #pragma unroll
    for (int r = 0; r < 4; ++r) pm = fmaxf(pm, s[n][r]);
  pm = fmaxf(pm, __shfl_xor(pm, 16));
  pm = fmaxf(pm, __shfl_xor(pm, 32));
  if (!__all(pm <= m + 8.0f)) {   // defer-max THR=8 (log2 units)
    float nm = fmaxf(m, pm);
    float corr = exp2f(m - nm);
    m = nm; l *= corr;
    float cf[4];
    #pragma unroll
    for (int r = 0; r < 4; ++r) cf[r] = __shfl(corr, g * 4 + r);
    #pragma unroll
    for (int dblk = 0; dblk < 4; ++dblk)
      #pragma unroll
      for (int r = 0; r < 4; ++r) o[dblk][r] *= cf[r];
  }
  float rs = 0.0f;
  #pragma unroll
  for (int n = 0; n < 4; ++n)
    #pragma unroll
    for (int r = 0; r < 4; ++r) {
      float p = exp2f(s[n][r] - m);
      s[n][r] = p; rs += p;
    }
  rs += __shfl_xor(rs, 16);
  rs += __shfl_xor(rs, 32);
  l += rs;
}

__device__ __forceinline__ void build_pa(const f32x4 (&s)[4], U8 (&pa)[2],
                                         int g, int c15) {
  unsigned pk[4][2];
  #pragma unroll
  for (int n = 0; n < 4; ++n) {
    pk[n][0] = cvtpk(s[n][0], s[n][1]);
    pk[n][1] = cvtpk(s[n][2], s[n][3]);
  }
  #pragma unroll
  for (int kh = 0; kh < 2; ++kh) {
    #pragma unroll
    for (int widx = 0; widx < 4; ++widx) {
      int src = (2 * (g & 1) + (widx >> 1)) * 16 + c15;
      unsigned lo = __shfl(pk[2 * kh][widx & 1], src);
      unsigned hi = __shfl(pk[2 * kh + 1][widx & 1], src);
      pa[kh].u[widx] = (g & 2) ? hi : lo;
    }
  }
}

// ---------------- causal flash attention: R10 base + SOFTMAX PIPELINED 1 TILE BEHIND ----------------
// Body t: QK^T(t) [MFMA, Kl buf t&1] || softmax+PV(t-1) [VALU+MFMA, Vt buf (t-1)&1].
// V staged one tile behind K: V(t) written into Vt[t&1] during body t, consumed body t+1.
// Parity: all reads/writes land on opposite buffers -> one lgkm barrier per tile, race-free.
// 2-deep reg prefetch for K (t+2), 1-deep for V (t+1). 45 scheds x 32 bh, KV-split qt>=19.
__global__ __launch_bounds__(256, 4) void k_flash(const short* __restrict__ Qb,
                                                  const short* __restrict__ Kb,
                                                  const short* __restrict__ Vb,
                                                  short* __restrict__ Ctx,
                                                  float* __restrict__ pO,
                                                  float* __restrict__ pML) {
  __shared__ __align__(16) short Vt[2][64][72];  // V[kv][d] at Vt[d][kv^((d>>4)<<3)]
  __shared__ __align__(16) short Kl[2][4096];    // K[kv][d] at kv*64 + ((d>>3)^(kv&7))*8 + (d&7)
  const int bid = blockIdx.x;
  const int sched = bid >> 5, bh = bid & 31;
  int qt, t0, t1, sid = 0; bool split;
  if (sched < 19) { qt = 18 - sched; t0 = 0; t1 = qt; split = false; }
  else {
    int j = sched - 19; qt = 31 - (j >> 1);
    int h1 = (qt + 2) >> 1;                       // ceil((qt+1)/2)
    if ((j & 1) == 0) { t0 = h1; t1 = qt; }       // late half
    else              { t0 = 0;  t1 = h1 - 1; }   // early half
    split = true; sid = bh * 26 + j;
  }
  const int b   = bh >> 4, h = bh & 15;
  const int tid = threadIdx.x, w = tid >> 6, lane = tid & 63;
  const int g   = lane >> 4, c15 = lane & 15;
  const int qg0 = qt * 64 + w * 16;
  const int qabs = qg0 + c15;

  const short* qp = Qb + ((size_t)(b * S_ + qabs)) * D_ + h * DH_ + g * 8;
  bf16x8 qf0 = *(const bf16x8*)qp;
  bf16x8 qf1 = *(const bf16x8*)(qp + 32);

  const int vkv = lane;
  const int vd0 = w * 16;
  const int vcol = vkv ^ (w << 3);
  const short* vrow = Vb + (size_t)b * S_ * D_ + h * DH_ + vd0;

  const short* kbase = Kb + (size_t)b * S_ * D_ + h * DH_;
  const int kidx0 = w * 128 + lane;
  const int kkv0 = kidx0 >> 3, kdb0 = (kidx0 & 7) ^ (kkv0 & 7);
  const int kidx1 = kidx0 + 64;
  const int kkv1 = kidx1 >> 3, kdb1 = (kidx1 & 7) ^ (kkv1 & 7);

  f32x4 o[4] = {};
  float m = -1e30f, l = 0.0f;
  f32x4 sA[4], sB[4];          // pipelined score sets (cur/prev alternate)
  bool havep = false;

  // staging regs: kc/vc hold K(t+1)/V(t) at top of body t; kn/vn receive K(t+2)/V(t+1)
  bf16x8 kc0, kc1, vc0, vc1, kn0, kn1, vn0, vn1;

  // prologue: K(t0) -> LDS; issue kc=K(t0+1), vc=V(t0)
  {
    const short* kb0 = kbase + (size_t)(t0 * 64) * D_;
    bf16x8 tk0 = *(const bf16x8*)(kb0 + (size_t)kkv0 * D_ + kdb0 * 8);
    bf16x8 tk1 = *(const bf16x8*)(kb0 + (size_t)kkv1 * D_ + kdb1 * 8);
    *(bf16x8*)&Kl[t0 & 1][kidx0 * 8] = tk0;
    *(bf16x8*)&Kl[t0 & 1][kidx1 * 8] = tk1;
    const short* vp = vrow + (size_t)(t0 * 64 + vkv) * D_;
    vc0 = *(const bf16x8*)vp;
    vc1 = *(const bf16x8*)(vp + 8);
    if (t0 + 1 <= t1) {
      const short* kb1 = kbase + (size_t)((t0 + 1) * 64) * D_;
      kc0 = *(const bf16x8*)(kb1 + (size_t)kkv0 * D_ + kdb0 * 8);
      kc1 = *(const bf16x8*)(kb1 + (size_t)kkv1 * D_ + kdb1 * 8);
    }
  }
  RAW_BARRIER();

  // body T: loads(K T+2 -> KN, V T+1 -> VN); QK(T)->SC; SM+PV(T-1) on SP (Vt[(T+1)&1]);
  //         write KC->Kl[(T+1)&1], VC->Vt[T&1]; barrier.
#define FBODY(T, KC0, KC1, VC0, VC1, KN0, KN1, VN0, VN1, SC, SP) do {           \
    const int kv0 = (T) * 64;                                                   \
    if ((T) + 2 <= t1) {                                                        \
      const short* kb2 = kbase + (size_t)(kv0 + 128) * D_;                      \
      KN0 = *(const bf16x8*)(kb2 + (size_t)kkv0 * D_ + kdb0 * 8);               \
      KN1 = *(const bf16x8*)(kb2 + (size_t)kkv1 * D_ + kdb1 * 8);               \
    }                                                                           \
    if ((T) + 1 <= t1) {                                                        \
      const short* vp2 = vrow + (size_t)(kv0 + 64 + vkv) * D_;                  \
      VN0 = *(const bf16x8*)vp2;                                                \
      VN1 = *(const bf16x8*)(vp2 + 8);                                          \
    }                                                                           \
    {                                                                           \
      const short* ks = &Kl[(T) & 1][0];                                        \
      __builtin_amdgcn_s_setprio(1);                                            \
      _Pragma("unroll")                                                         \
      for (int n = 0; n < 4; ++n) {                                             \
        int krow = (n * 16 + c15) * 64;                                         \
        bf16x8 k0 = *(const bf16x8*)&ks[krow + ((g ^ (c15 & 7)) * 8)];          \
        bf16x8 k1 = *(const bf16x8*)&ks[krow + (((g + 4) ^ (c15 & 7)) * 8)];    \
        f32x4 z = {0.0f, 0.0f, 0.0f, 0.0f};                                     \
        z = MFMA16(k0, qf0, z);                                                 \
        SC[n] = MFMA16(k1, qf1, z);                                             \
      }                                                                         \
      __builtin_amdgcn_s_setprio(0);                                            \
      if (kv0 + 63 > qg0) {                                                     \
        _Pragma("unroll")                                                       \
        for (int n = 0; n < 4; ++n)                                             \
          _Pragma("unroll")                                                     \
          for (int r = 0; r < 4; ++r)                                           \
            if (kv0 + n * 16 + g * 4 + r > qabs) SC[n][r] = -1e30f;             \
      }                                                                         \
    }                                                                           \
    if (havep) {                                                                \
      softmax_g(SP, m, l, o, g);                                                \
      U8 pa[2];                                                                 \
      build_pa(SP, pa, g, c15);                                                 \
      __builtin_amdgcn_s_setprio(1);                                            \
      _Pragma("unroll")                                                         \
      for (int kh = 0; kh < 2; ++kh)                                            \
        _Pragma("unroll")                                                       \
        for (int dblk = 0; dblk < 4; ++dblk) {                                  \
          bf16x8 vbf = *(const bf16x8*)&Vt[((T) + 1) & 1][dblk * 16 + c15]      \
                                         [kh * 32 + ((g ^ dblk) * 8)];          \
          o[dblk] = MFMA16(pa[kh].v, vbf, o[dblk]);                             \
        }                                                                       \
      __builtin_amdgcn_s_setprio(0);                                            \
    }                                                                           \
    havep = true;                                                               \
    if ((T) + 1 <= t1) {                                                        \
      *(bf16x8*)&Kl[((T) + 1) & 1][kidx0 * 8] = KC0;                            \
      *(bf16x8*)&Kl[((T) + 1) & 1][kidx1 * 8] = KC1;                            \
    }                                                                           \
    _Pragma("unroll")                                                           \
    for (int j = 0; j < 8; ++j) Vt[(T) & 1][vd0 + j][vcol] = VC0[j];            \
    _Pragma("unroll")                                                           \
    for (int j = 0; j < 8; ++j) Vt[(T) & 1][vd0 + 8 + j][vcol] = VC1[j];        \
    RAW_BARRIER();                                                              \
  } while (0)

  for (int t = t0; t <= t1; ) {
    FBODY(t, kc0, kc1, vc0, vc1, kn0, kn1, vn0, vn1, sA, sB);
    ++t;
    if (t > t1) break;
    FBODY(t, kn0, kn1, vn0, vn1, kc0, kc1, vc0, vc1, sB, sA);
    ++t;
  }
#undef FBODY

  // drain: softmax + PV for tile t1 (scores in sA if even body count, else sB)
  if (havep) {
    U8 pa[2];
    if (((t1 - t0) & 1) == 0) {
      softmax_g(sA, m, l, o, g);
      build_pa(sA, pa, g, c15);
    } else {
      softmax_g(sB, m, l, o, g);
      build_pa(sB, pa, g, c15);
    }
    __builtin_amdgcn_s_setprio(1);
    #pragma unroll
    for (int kh = 0; kh < 2; ++kh)
      #pragma unroll
      for (int dblk = 0; dblk < 4; ++dblk) {
        bf16x8 vbf = *(const bf16x8*)&Vt[t1 & 1][dblk * 16 + c15]
                                       [kh * 32 + ((g ^ dblk) * 8)];
        o[dblk] = MFMA16(pa[kh].v, vbf, o[dblk]);
      }
    __builtin_amdgcn_s_setprio(0);
  }

  if (!split) {
    float linv = 1.0f / l;
    float lf[4];
    #pragma unroll
    for (int r = 0; r < 4; ++r) lf[r] = __shfl(linv, g * 4 + r);
    #pragma unroll
    for (int dblk = 0; dblk < 4; ++dblk)
      #pragma unroll
      for (int r = 0; r < 4; ++r) {
        int q = qg0 + g * 4 + r;
        Ctx[((size_t)(b * S_ + q)) * D_ + h * DH_ + dblk * 16 + c15] = f2bf(o[dblk][r] * lf[r]);
      }
  } else {
    float* po = pO + ((size_t)sid * 64 + w * 16) * 64;
    #pragma unroll
    for (int dblk = 0; dblk < 4; ++dblk)
      #pragma unroll
      for (int r = 0; r < 4; ++r)
        po[(g * 4 + r) * 64 + dblk * 16 + c15] = o[dblk][r];
    if (lane < 16) {
      pML[(size_t)sid * 128 + w * 16 + lane]      = m;
      pML[(size_t)sid * 128 + 64 + w * 16 + lane] = l;
    }
  }
}

// ---------------- combine split halves: ctx rows for qt in [19,31] ----------------
__global__ __launch_bounds__(256) void k_combine(const float* __restrict__ pO,
                                                 const float* __restrict__ pML,
                                                 short* __restrict__ Ctx) {
  const int p = blockIdx.x;           // 13 qt x 32 bh
  const int qt = 19 + (p >> 5), bh = p & 31;
  const int b = bh >> 4, h = bh & 15;
  const int jb = (31 - qt) * 2;
  const int sidB = bh * 26 + jb;      // late half
  const int sidA = bh * 26 + jb + 1;  // early half
  const int q = threadIdx.x >> 2;
  const int d0 = (threadIdx.x & 3) * 16;
  float mA = pML[(size_t)sidA * 128 + q], lA = pML[(size_t)sidA * 128 + 64 + q];
  float mB = pML[(size_t)sidB * 128 + q], lB = pML[(size_t)sidB * 128 + 64 + q];
  float M = fmaxf(mA, mB);
  float wA = exp2f(mA - M), wB = exp2f(mB - M);
  float inv = 1.0f / (lA * wA + lB * wB);
  const float* oA = pO + ((size_t)sidA * 64 + q) * 64 + d0;
  const float* oB = pO + ((size_t)sidB * 64 + q) * 64 + d0;
  short* cp = Ctx + ((size_t)(b * S_ + qt * 64 + q)) * D_ + h * DH_ + d0;
  #pragma unroll
  for (int i = 0; i < 16; i += 4) {
    float4 a = *(const float4*)(oA + i);
    float4 c = *(const float4*)(oB + i);
    cp[i + 0] = f2bf((a.x * wA + c.x * wB) * inv);
    cp[i + 1] = f2bf((a.y * wA + c.y * wB) * inv);
    cp[i + 2] = f2bf((a.z * wA + c.z * wB) * inv);
    cp[i + 3] = f2bf((a.w * wA + c.w * wB) * inv);
  }
}

extern "C" void kernel_launch(void* const* d_in, const int* in_sizes, int n_in,
                              void* d_out, int out_size, void* d_ws, size_t ws_size,
                              hipStream_t stream) {
  (void)in_sizes; (void)n_in; (void)out_size; (void)ws_size;
  const float* x  = (const float*)d_in[0];
  const float* Wq = (const float*)d_in[1];
  const float* bq = (const float*)d_in[2];
  const float* Wk = (const float*)d_in[3];
  const float* bk = (const float*)d_in[4];
  const float* Wv = (const float*)d_in[5];
  const float* bv = (const float*)d_in[6];
  const float* Wo = (const float*)d_in[7];
  const float* bo = (const float*)d_in[8];
  float* out = (float*)d_out;
  char* ws = (char*)d_ws;

  const size_t MS = (size_t)B_ * S_;  // 4096
  short* xb  = (short*)(ws);                                  // 8 MB (pre-flash)
  short* wqT = (short*)(ws + (size_t)8 * 1024 * 1024);        // 2 MB each, contiguous
  short* wkT = wqT + (size_t)D_ * D_;
  short* wvT = wkT + (size_t)D_ * D_;
  short* woT = wvT + (size_t)D_ * D_;                         // needed till the end
  short* qb  = (short*)(ws + (size_t)16 * 1024 * 1024);       // 8 MB each
  short* kb  = qb + MS * D_;
  short* vb  = kb + MS * D_;
  short* ctx = vb + MS * D_;
  float* cosT = (float*)(ws + (size_t)48 * 1024 * 1024);      // 256 KB each
  float* sinT = cosT + (size_t)S_ * 32;
  // flash partials: pO aliases [0,14MB) (xb+wqT/wkT/wvT, dead after qkv GEMM);
  // 832 slots x 64 rows x 64 f32 = 13.3 MB. pML: 832 x 128 f32 = 426 KB.
  float* pO  = (float*)(ws);
  float* pML = (float*)(ws + (size_t)48 * 1024 * 1024 + 512 * 1024);

  // 1. x -> bf16 + rope table (fused)
  k_cvt_table<<<dim3(4096 + 256), 256, 0, stream>>>(x, xb, cosT, sinT);
  // 2. weights -> bf16 transposed (one launch; wqT..woT contiguous)
  k_transpose4<<<dim3(32, 32, 4), dim3(32, 8), 0, stream>>>(Wq, Wk, Wv, Wo, wqT);
  // 3. fused QKV projection + bias + RoPE (+ (1/8)*log2e fold into Q)
  k_gemm_qkv<<<dim3(24, 32), 256, 0, stream>>>(xb, wqT, bq, bk, bv, cosT, sinT, qb, kb, vb);
  // 4. causal flash attention (pipelined softmax, 1 barrier/tile)
  k_flash<<<dim3(45 * 32), 256, 0, stream>>>(qb, kb, vb, ctx, pO, pML);
  // 5. combine split halves (qt 19..31)
  k_combine<<<dim3(13 * 32), 256, 0, stream>>>(pO, pML, ctx);
  // 6. output projection (f32 out)
  k_gemm<<<dim3(8, 32), 256, 0, stream>>>(ctx, woT, bo, out, 4096, 1024, 1024);
}

// Round 16
// 135.698 us; speedup vs baseline: 2.1597x; 2.1597x over previous
//
#include <hip/hip_runtime.h>
#include <hip/hip_bf16.h>

#define B_  2
#define S_  2048
#define D_  1024
#define H_  16
#define DH_ 64

typedef __attribute__((ext_vector_type(8))) short bf16x8;
typedef __attribute__((ext_vector_type(4))) float f32x4;

__device__ __forceinline__ short f2bf(float f) {
  unsigned int u; __builtin_memcpy(&u, &f, 4);
  u = (u + 0x7FFFu + ((u >> 16) & 1u)) >> 16;
  return (short)u;
}
// packed f32x2 -> bf16x2 (RNE), lo = first arg
__device__ __forceinline__ unsigned cvtpk(float a, float b) {
  unsigned r;
  asm("v_cvt_pk_bf16_f32 %0, %1, %2" : "=v"(r) : "v"(a), "v"(b));
  return r;
}

#define GLOAD_LDS16(gp, lp) \
  __builtin_amdgcn_global_load_lds((const __attribute__((address_space(1))) void*)(gp), \
                                   (__attribute__((address_space(3))) void*)(lp), 16, 0, 0)

#define MFMA16(a, b, c) __builtin_amdgcn_mfma_f32_16x16x32_bf16(a, b, c, 0, 0, 0)

// lgkm-only barrier: LDS writes visible, in-flight global loads NOT drained.
#define RAW_BARRIER() do {                                   \
    asm volatile("s_waitcnt lgkmcnt(0)" ::: "memory");       \
    __builtin_amdgcn_s_barrier();                            \
    asm volatile("" ::: "memory");                           \
  } while (0)

union U8 { unsigned u[4]; bf16x8 v; };

// ---------------- f32 -> bf16 convert (x) + RoPE table (fused) ----------------
__global__ __launch_bounds__(256) void k_cvt_table(const float* __restrict__ in,
                                                   short* __restrict__ out,
                                                   float* __restrict__ cosT,
                                                   float* __restrict__ sinT) {
  int bid = blockIdx.x;
  if (bid < 4096) {                      // cvt: 4096 blocks x 256 thr x float4
    int i = bid * 256 + threadIdx.x;
    float4 v = ((const float4*)in)[i];
    short4 o; o.x = f2bf(v.x); o.y = f2bf(v.y); o.z = f2bf(v.z); o.w = f2bf(v.w);
    *(short4*)(out + (size_t)i * 4) = o;
  } else {                               // table: 256 blocks (S*32 entries)
    int i = (bid - 4096) * 256 + threadIdx.x;
    int s = i >> 5, d = i & 31;
    float invf = exp2f(-(float)d * (13.287712379549449f / 32.0f)); // 10000^(-d/32)
    float ang = (float)s * invf;
    cosT[i] = cosf(ang);
    sinT[i] = sinf(ang);
  }
}

// ---------------- 4 weights (f32 [K][N]) -> Wt (bf16 [N][K]), one launch ----------------
__global__ __launch_bounds__(256) void k_transpose4(const float* __restrict__ W0,
                                                    const float* __restrict__ W1,
                                                    const float* __restrict__ W2,
                                                    const float* __restrict__ W3,
                                                    short* __restrict__ WtBase) {
  __shared__ float tile[32][33];
  const float* W = (blockIdx.z == 0) ? W0 : (blockIdx.z == 1) ? W1 :
                   (blockIdx.z == 2) ? W2 : W3;
  short* Wt = WtBase + (size_t)blockIdx.z * D_ * D_;
  int tx = threadIdx.x, ty = threadIdx.y;
  int bx = blockIdx.x * 32, by = blockIdx.y * 32;
  #pragma unroll
  for (int i = 0; i < 32; i += 8)
    tile[ty + i][tx] = W[(size_t)(by + ty + i) * D_ + bx + tx];
  __syncthreads();
  #pragma unroll
  for (int i = 0; i < 32; i += 8)
    Wt[(size_t)(bx + ty + i) * D_ + by + tx] = f2bf(tile[tx][ty + i]);
}

// ---------------- fused QKV GEMM + bias + RoPE epilogue (XCD-swizzled grid) ----------------
__global__ __launch_bounds__(256) void k_gemm_qkv(const short* __restrict__ A,
                                                  const short* __restrict__ Bt,
                                                  const float* __restrict__ bq,
                                                  const float* __restrict__ bk,
                                                  const float* __restrict__ bv,
                                                  const float* __restrict__ cosT,
                                                  const float* __restrict__ sinT,
                                                  short* __restrict__ qb,
                                                  short* __restrict__ kb,
                                                  short* __restrict__ vb) {
  const int K = 1024;
  __shared__ __align__(16) short lA[128 * 32];
  __shared__ __align__(16) short lB[128 * 32];
  // XCD-bijective swizzle: 768 blocks (%8==0), chunk = 96 per XCD
  const int fid = blockIdx.y * 24 + blockIdx.x;
  const int swz = (fid & 7) * 96 + (fid >> 3);
  const int bxs = swz % 24, bys = swz / 24;
  const int tid = threadIdx.x;
  const int wid = tid >> 6, lane = tid & 63;
  const int brow = bys * 128, bcol = bxs * 128;
  const int wr = wid >> 1, wc = wid & 1;
  const int g = lane >> 4, c15 = lane & 15;
  const int sr = lane >> 2, scol = (lane & 3) * 8;
  f32x4 acc[4][4] = {};

  for (int kt = 0; kt < K; kt += 32) {
    __syncthreads();
    #pragma unroll
    for (int ch = 0; ch < 2; ++ch) {
      const short* ga = A + (size_t)(brow + ch * 64 + wid * 16 + sr) * K + kt + scol;
      const short* gb = Bt + (size_t)(bcol + ch * 64 + wid * 16 + sr) * K + kt + scol;
      GLOAD_LDS16(ga, &lA[(ch * 64 + wid * 16) * 32]);
      GLOAD_LDS16(gb, &lB[(ch * 64 + wid * 16) * 32]);
    }
    __syncthreads();
    bf16x8 af[4], bfr[4];
    #pragma unroll
    for (int mi = 0; mi < 4; ++mi)
      af[mi] = *(const bf16x8*)&lA[(wr * 64 + mi * 16 + c15) * 32 + g * 8];
    #pragma unroll
    for (int ni = 0; ni < 4; ++ni)
      bfr[ni] = *(const bf16x8*)&lB[(wc * 64 + ni * 16 + c15) * 32 + g * 8];
    #pragma unroll
    for (int mi = 0; mi < 4; ++mi)
      #pragma unroll
      for (int ni = 0; ni < 4; ++ni)
        acc[mi][ni] = MFMA16(af[mi], bfr[ni], acc[mi][ni]);
  }

  const int seg = bcol >> 10;                       // 0=q 1=k 2=v
  const float* bp = (seg == 0) ? bq : (seg == 1) ? bk : bv;
  short* dst = (seg == 0) ? qb : (seg == 1) ? kb : vb;
  const float alpha = (seg == 0) ? 0.18033688f : 1.0f;  // (1/8)*log2(e)
  const bool rope = (seg < 2);
  #pragma unroll
  for (int mi = 0; mi < 4; ++mi) {
    #pragma unroll
    for (int ni = 0; ni < 2; ++ni) {
      int col  = bcol + wc * 64 + ni * 16 + c15;
      int lcol = col & 1023;
      int d    = col & 63;                          // 0..31 (ni<2)
      float b1 = bp[lcol], b2 = bp[lcol + 32];
      #pragma unroll
      for (int r = 0; r < 4; ++r) {
        int row = brow + wr * 64 + mi * 16 + g * 4 + r;
        float x1 = (acc[mi][ni][r]     + b1) * alpha;
        float x2 = (acc[mi][ni + 2][r] + b2) * alpha;
        float o1 = x1, o2 = x2;
        if (rope) {
          int s = row & (S_ - 1);
          float co = cosT[s * 32 + d], si = sinT[s * 32 + d];
          o1 = x1 * co - x2 * si;
          o2 = x1 * si + x2 * co;
        }
        dst[(size_t)row * 1024 + lcol]      = f2bf(o1);
        dst[(size_t)row * 1024 + lcol + 32] = f2bf(o2);
      }
    }
  }
}

// ---------------- bf16 GEMM (Wo): C = A*Bt^T + bias(col), f32 out ----------------
__global__ __launch_bounds__(256) void k_gemm(const short* __restrict__ A,
                                              const short* __restrict__ Bt,
                                              const float* __restrict__ bias,
                                              float* __restrict__ out,
                                              int M, int N, int K) {
  __shared__ __align__(16) short lA[128 * 32];
  __shared__ __align__(16) short lB[128 * 32];
  // XCD-bijective swizzle: 256 blocks (%8==0), chunk = 32 per XCD
  const int fid = blockIdx.y * 8 + blockIdx.x;
  const int swz = (fid & 7) * 32 + (fid >> 3);
  const int bxs = swz % 8, bys = swz / 8;
  const int tid = threadIdx.x;
  const int wid = tid >> 6, lane = tid & 63;
  const int brow = bys * 128, bcol = bxs * 128;
  const int wr = wid >> 1, wc = wid & 1;
  const int g = lane >> 4, c15 = lane & 15;
  const int sr = lane >> 2, scol = (lane & 3) * 8;
  f32x4 acc[4][4] = {};

  for (int kt = 0; kt < K; kt += 32) {
    __syncthreads();
    #pragma unroll
    for (int ch = 0; ch < 2; ++ch) {
      const short* ga = A + (size_t)(brow + ch * 64 + wid * 16 + sr) * K + kt + scol;
      const short* gb = Bt + (size_t)(bcol + ch * 64 + wid * 16 + sr) * K + kt + scol;
      GLOAD_LDS16(ga, &lA[(ch * 64 + wid * 16) * 32]);
      GLOAD_LDS16(gb, &lB[(ch * 64 + wid * 16) * 32]);
    }
    __syncthreads();
    bf16x8 af[4], bfr[4];
    #pragma unroll
    for (int mi = 0; mi < 4; ++mi)
      af[mi] = *(const bf16x8*)&lA[(wr * 64 + mi * 16 + c15) * 32 + g * 8];
    #pragma unroll
    for (int ni = 0; ni < 4; ++ni)
      bfr[ni] = *(const bf16x8*)&lB[(wc * 64 + ni * 16 + c15) * 32 + g * 8];
    #pragma unroll
    for (int mi = 0; mi < 4; ++mi)
      #pragma unroll
      for (int ni = 0; ni < 4; ++ni)
        acc[mi][ni] = MFMA16(af[mi], bfr[ni], acc[mi][ni]);
  }

  #pragma unroll
  for (int mi = 0; mi < 4; ++mi) {
    #pragma unroll
    for (int ni = 0; ni < 4; ++ni) {
      int col = bcol + wc * 64 + ni * 16 + c15;
      float bv = bias[col];
      #pragma unroll
      for (int r = 0; r < 4; ++r) {
        int row = brow + wr * 64 + mi * 16 + g * 4 + r;
        out[(size_t)row * N + col] = acc[mi][ni][r] + bv;
      }
    }
  }
}

// ---- flash helpers (validated R5/R7 layouts) ----
__device__ __forceinline__ void softmax_g(f32x4 (&s)[4], float& m, float& l,
                                          f32x4 (&o)[4], int g) {
  float pm = -1e30f;
  #pragma unroll
  for (int n = 0; n < 4; ++n)
    #pragma unroll
    for (int r = 0; r < 4; ++r) pm = fmaxf(pm, s[n][r]);
  pm = fmaxf(pm, __shfl_xor(pm, 16));
  pm = fmaxf(pm, __shfl_xor(pm, 32));
  if (!__all(pm <= m + 8.0f)) {   // defer-max THR=8 (log2 units)
    float nm = fmaxf(m, pm);
    float corr = exp2f(m - nm);
    m = nm; l *= corr;
    float cf[4];
    #pragma unroll
    for (int r = 0; r < 4; ++r) cf[r] = __shfl(corr, g * 4 + r);
    #pragma unroll
    for (int dblk = 0; dblk < 4; ++dblk)
      #pragma unroll
      for (int r = 0; r < 4; ++r) o[dblk][r] *= cf[r];
  }
  float rs = 0.0f;
  #pragma unroll
  for (int n = 0; n < 4; ++n)
    #pragma unroll
    for (int r = 0; r < 4; ++r) {
      float p = exp2f(s[n][r] - m);
      s[n][r] = p; rs += p;
    }
  rs += __shfl_xor(rs, 16);
  rs += __shfl_xor(rs, 32);
  l += rs;
}

__device__ __forceinline__ void build_pa(const f32x4 (&s)[4], U8 (&pa)[2],
                                         int g, int c15) {
  unsigned pk[4][2];
  #pragma unroll
  for (int n = 0; n < 4; ++n) {
    pk[n][0] = cvtpk(s[n][0], s[n][1]);
    pk[n][1] = cvtpk(s[n][2], s[n][3]);
  }
  #pragma unroll
  for (int kh = 0; kh < 2; ++kh) {
    #pragma unroll
    for (int widx = 0; widx < 4; ++widx) {
      int src = (2 * (g & 1) + (widx >> 1)) * 16 + c15;
      unsigned lo = __shfl(pk[2 * kh][widx & 1], src);
      unsigned hi = __shfl(pk[2 * kh + 1][widx & 1], src);
      pa[kh].u[widx] = (g & 2) ? hi : lo;
    }
  }
}

// ---------------- causal flash attention (R7 base + 2-deep reg-staged prefetch) ----------------
// 4 waves/block, wave owns 16 q-rows (qt*64 + w*16). KV tile 64, K+V double-buffered
// in LDS, BOTH reg-staged 2 tiles ahead; raw barrier (lgkmcnt only) never drains the
// in-flight t+2 global loads. 45 scheds x 32 bh, KV-split for qt>=19.
__global__ __launch_bounds__(256, 4) void k_flash(const short* __restrict__ Qb,
                                                  const short* __restrict__ Kb,
                                                  const short* __restrict__ Vb,
                                                  short* __restrict__ Ctx,
                                                  float* __restrict__ pO,
                                                  float* __restrict__ pML) {
  __shared__ __align__(16) short Vt[2][64][72];  // V[kv][d] at Vt[d][kv^((d>>4)<<3)]
  __shared__ __align__(16) short Kl[2][4096];    // K[kv][d] at kv*64 + ((d>>3)^(kv&7))*8 + (d&7)
  const int bid = blockIdx.x;
  const int sched = bid >> 5, bh = bid & 31;
  int qt, t0, t1, sid = 0; bool split;
  if (sched < 19) { qt = 18 - sched; t0 = 0; t1 = qt; split = false; }
  else {
    int j = sched - 19; qt = 31 - (j >> 1);
    int h1 = (qt + 2) >> 1;                       // ceil((qt+1)/2)
    if ((j & 1) == 0) { t0 = h1; t1 = qt; }       // late half
    else              { t0 = 0;  t1 = h1 - 1; }   // early half
    split = true; sid = bh * 26 + j;
  }
  const int b   = bh >> 4, h = bh & 15;
  const int tid = threadIdx.x, w = tid >> 6, lane = tid & 63;
  const int g   = lane >> 4, c15 = lane & 15;
  const int qg0 = qt * 64 + w * 16;
  const int qabs = qg0 + c15;

  // Q fragments (B-operand of swapped QK^T)
  const short* qp = Qb + ((size_t)(b * S_ + qabs)) * D_ + h * DH_ + g * 8;
  bf16x8 qf0 = *(const bf16x8*)qp;
  bf16x8 qf1 = *(const bf16x8*)(qp + 32);

  // V staging: wave w stages d-slice [w*16, +16) for all 64 kv (lane = kv)
  const int vkv = lane;
  const int vd0 = w * 16;
  const int vcol = vkv ^ (w << 3);
  const short* vrow = Vb + (size_t)b * S_ * D_ + h * DH_ + vd0;

  // K staging addresses (reg-staged): thread covers kidx0, kidx1 (16B each)
  const short* kbase = Kb + (size_t)b * S_ * D_ + h * DH_;
  const int kidx0 = w * 128 + lane;
  const int kkv0 = kidx0 >> 3, kdb0 = (kidx0 & 7) ^ (kkv0 & 7);
  const int kidx1 = kidx0 + 64;
  const int kkv1 = kidx1 >> 3, kdb1 = (kidx1 & 7) ^ (kkv1 & 7);

  f32x4 o[4] = {};
  float m = -1e30f, l = 0.0f;

  // staging register sets: c = holds tile t+1 at top of body t; n = receives t+2
  bf16x8 kc0, kc1, vc0, vc1, kn0, kn1, vn0, vn1;

  // prologue: load+write tile t0, then issue loads for t0+1 into the hold set
  {
    const short* kb0 = kbase + (size_t)(t0 * 64) * D_;
    bf16x8 tk0 = *(const bf16x8*)(kb0 + (size_t)kkv0 * D_ + kdb0 * 8);
    bf16x8 tk1 = *(const bf16x8*)(kb0 + (size_t)kkv1 * D_ + kdb1 * 8);
    const short* vp = vrow + (size_t)(t0 * 64 + vkv) * D_;
    bf16x8 tv0 = *(const bf16x8*)vp;
    bf16x8 tv1 = *(const bf16x8*)(vp + 8);
    *(bf16x8*)&Kl[t0 & 1][kidx0 * 8] = tk0;
    *(bf16x8*)&Kl[t0 & 1][kidx1 * 8] = tk1;
    #pragma unroll
    for (int j = 0; j < 8; ++j) Vt[t0 & 1][vd0 + j][vcol] = tv0[j];
    #pragma unroll
    for (int j = 0; j < 8; ++j) Vt[t0 & 1][vd0 + 8 + j][vcol] = tv1[j];
    if (t0 + 1 <= t1) {
      const short* kb1 = kbase + (size_t)((t0 + 1) * 64) * D_;
      kc0 = *(const bf16x8*)(kb1 + (size_t)kkv0 * D_ + kdb0 * 8);
      kc1 = *(const bf16x8*)(kb1 + (size_t)kkv1 * D_ + kdb1 * 8);
      const short* vp1 = vrow + (size_t)((t0 + 1) * 64 + vkv) * D_;
      vc0 = *(const bf16x8*)vp1;
      vc1 = *(const bf16x8*)(vp1 + 8);
    }
  }
  RAW_BARRIER();   // lgkm only: t0+1 loads stay in flight

  // body: issue loads(T+2)->N; compute T; write C(=T+1)->LDS; raw barrier
#define FBODY(T, KC0, KC1, VC0, VC1, KN0, KN1, VN0, VN1) do {                   \
    const int kv0 = (T) * 64;                                                   \
    if ((T) + 2 <= t1) {                                                        \
      const short* kb2 = kbase + (size_t)(kv0 + 128) * D_;                      \
      KN0 = *(const bf16x8*)(kb2 + (size_t)kkv0 * D_ + kdb0 * 8);               \
      KN1 = *(const bf16x8*)(kb2 + (size_t)kkv1 * D_ + kdb1 * 8);               \
      const short* vp2 = vrow + (size_t)(kv0 + 128 + vkv) * D_;                 \
      VN0 = *(const bf16x8*)vp2;                                                \
      VN1 = *(const bf16x8*)(vp2 + 8);                                          \
    }                                                                           \
    if (kv0 <= qg0 + 15) {                                                      \
      const short* ks = &Kl[(T) & 1][0];                                        \
      f32x4 s[4] = {};                                                          \
      __builtin_amdgcn_s_setprio(1);                                            \
      _Pragma("unroll")                                                         \
      for (int n = 0; n < 4; ++n) {                                             \
        int krow = (n * 16 + c15) * 64;                                         \
        bf16x8 k0 = *(const bf16x8*)&ks[krow + ((g ^ (c15 & 7)) * 8)];          \
        bf16x8 k1 = *(const bf16x8*)&ks[krow + (((g + 4) ^ (c15 & 7)) * 8)];    \
        s[n] = MFMA16(k0, qf0, s[n]);                                           \
        s[n] = MFMA16(k1, qf1, s[n]);                                           \
      }                                                                         \
      __builtin_amdgcn_s_setprio(0);                                            \
      if (kv0 + 63 > qg0) {                                                     \
        _Pragma("unroll")                                                       \
        for (int n = 0; n < 4; ++n)                                             \
          _Pragma("unroll")                                                     \
          for (int r = 0; r < 4; ++r)                                           \
            if (kv0 + n * 16 + g * 4 + r > qabs) s[n][r] = -1e30f;              \
      }                                                                         \
      softmax_g(s, m, l, o, g);                                                 \
      U8 pa[2];                                                                 \
      build_pa(s, pa, g, c15);                                                  \
      __builtin_amdgcn_s_setprio(1);                                            \
      _Pragma("unroll")                                                         \
      for (int kh = 0; kh < 2; ++kh)                                            \
        _Pragma("unroll")                                                       \
        for (int dblk = 0; dblk < 4; ++dblk) {                                  \
          bf16x8 vbf = *(const bf16x8*)&Vt[(T) & 1][dblk * 16 + c15]            \
                                         [kh * 32 + ((g ^ dblk) * 8)];          \
          o[dblk] = MFMA16(pa[kh].v, vbf, o[dblk]);                             \
        }                                                                       \
      __builtin_amdgcn_s_setprio(0);                                            \
    }                                                                           \
    if ((T) + 1 <= t1) {                                                        \
      *(bf16x8*)&Kl[((T) + 1) & 1][kidx0 * 8] = KC0;                            \
      *(bf16x8*)&Kl[((T) + 1) & 1][kidx1 * 8] = KC1;                            \
      _Pragma("unroll")                                                         \
      for (int j = 0; j < 8; ++j) Vt[((T) + 1) & 1][vd0 + j][vcol] = VC0[j];    \
      _Pragma("unroll")                                                         \
      for (int j = 0; j < 8; ++j) Vt[((T) + 1) & 1][vd0 + 8 + j][vcol] = VC1[j];\
      RAW_BARRIER();                                                            \
    }                                                                           \
  } while (0)

  for (int t = t0; t <= t1; ) {
    FBODY(t, kc0, kc1, vc0, vc1, kn0, kn1, vn0, vn1);
    ++t;
    if (t > t1) break;
    FBODY(t, kn0, kn1, vn0, vn1, kc0, kc1, vc0, vc1);
    ++t;
  }
#undef FBODY

  if (!split) {
    // ---- epilogue: normalize, store ctx ----
    float linv = 1.0f / l;
    float lf[4];
    #pragma unroll
    for (int r = 0; r < 4; ++r) lf[r] = __shfl(linv, g * 4 + r);
    #pragma unroll
    for (int dblk = 0; dblk < 4; ++dblk)
      #pragma unroll
      for (int r = 0; r < 4; ++r) {
        int q = qg0 + g * 4 + r;
        Ctx[((size_t)(b * S_ + q)) * D_ + h * DH_ + dblk * 16 + c15] = f2bf(o[dblk][r] * lf[r]);
      }
  } else {
    // ---- epilogue: raw partial O (f32) + per-row m,l ----
    float* po = pO + ((size_t)sid * 64 + w * 16) * 64;
    #pragma unroll
    for (int dblk = 0; dblk < 4; ++dblk)
      #pragma unroll
      for (int r = 0; r < 4; ++r)
        po[(g * 4 + r) * 64 + dblk * 16 + c15] = o[dblk][r];
    if (lane < 16) {   // lanes 0..15: g=0, c15=lane -> row w*16+lane
      pML[(size_t)sid * 128 + w * 16 + lane]      = m;
      pML[(size_t)sid * 128 + 64 + w * 16 + lane] = l;
    }
  }
}

// ---------------- combine split halves: ctx rows for qt in [19,31] ----------------
__global__ __launch_bounds__(256) void k_combine(const float* __restrict__ pO,
                                                 const float* __restrict__ pML,
                                                 short* __restrict__ Ctx) {
  const int p = blockIdx.x;           // 13 qt x 32 bh
  const int qt = 19 + (p >> 5), bh = p & 31;
  const int b = bh >> 4, h = bh & 15;
  const int jb = (31 - qt) * 2;
  const int sidB = bh * 26 + jb;      // late half
  const int sidA = bh * 26 + jb + 1;  // early half
  const int q = threadIdx.x >> 2;
  const int d0 = (threadIdx.x & 3) * 16;
  float mA = pML[(size_t)sidA * 128 + q], lA = pML[(size_t)sidA * 128 + 64 + q];
  float mB = pML[(size_t)sidB * 128 + q], lB = pML[(size_t)sidB * 128 + 64 + q];
  float M = fmaxf(mA, mB);
  float wA = exp2f(mA - M), wB = exp2f(mB - M);
  float inv = 1.0f / (lA * wA + lB * wB);
  const float* oA = pO + ((size_t)sidA * 64 + q) * 64 + d0;
  const float* oB = pO + ((size_t)sidB * 64 + q) * 64 + d0;
  short* cp = Ctx + ((size_t)(b * S_ + qt * 64 + q)) * D_ + h * DH_ + d0;
  #pragma unroll
  for (int i = 0; i < 16; i += 4) {
    float4 a = *(const float4*)(oA + i);
    float4 c = *(const float4*)(oB + i);
    cp[i + 0] = f2bf((a.x * wA + c.x * wB) * inv);
    cp[i + 1] = f2bf((a.y * wA + c.y * wB) * inv);
    cp[i + 2] = f2bf((a.z * wA + c.z * wB) * inv);
    cp[i + 3] = f2bf((a.w * wA + c.w * wB) * inv);
  }
}

extern "C" void kernel_launch(void* const* d_in, const int* in_sizes, int n_in,
                              void* d_out, int out_size, void* d_ws, size_t ws_size,
                              hipStream_t stream) {
  (void)in_sizes; (void)n_in; (void)out_size; (void)ws_size;
  const float* x  = (const float*)d_in[0];
  const float* Wq = (const float*)d_in[1];
  const float* bq = (const float*)d_in[2];
  const float* Wk = (const float*)d_in[3];
  const float* bk = (const float*)d_in[4];
  const float* Wv = (const float*)d_in[5];
  const float* bv = (const float*)d_in[6];
  const float* Wo = (const float*)d_in[7];
  const float* bo = (const float*)d_in[8];
  float* out = (float*)d_out;
  char* ws = (char*)d_ws;

  const size_t MS = (size_t)B_ * S_;  // 4096
  short* xb  = (short*)(ws);                                  // 8 MB (pre-flash)
  short* wqT = (short*)(ws + (size_t)8 * 1024 * 1024);        // 2 MB each, contiguous
  short* wkT = wqT + (size_t)D_ * D_;
  short* wvT = wkT + (size_t)D_ * D_;
  short* woT = wvT + (size_t)D_ * D_;                         // needed till the end
  short* qb  = (short*)(ws + (size_t)16 * 1024 * 1024);       // 8 MB each
  short* kb  = qb + MS * D_;
  short* vb  = kb + MS * D_;
  short* ctx = vb + MS * D_;
  float* cosT = (float*)(ws + (size_t)48 * 1024 * 1024);      // 256 KB each
  float* sinT = cosT + (size_t)S_ * 32;
  // flash partials: pO aliases [0,14MB) (xb+wqT/wkT/wvT, dead after qkv GEMM);
  // 832 slots x 64 rows x 64 f32 = 13.3 MB. pML: 832 x 128 f32 = 426 KB.
  float* pO  = (float*)(ws);
  float* pML = (float*)(ws + (size_t)48 * 1024 * 1024 + 512 * 1024);

  // 1. x -> bf16 + rope table (fused)
  k_cvt_table<<<dim3(4096 + 256), 256, 0, stream>>>(x, xb, cosT, sinT);
  // 2. weights -> bf16 transposed (one launch; wqT..woT contiguous)
  k_transpose4<<<dim3(32, 32, 4), dim3(32, 8), 0, stream>>>(Wq, Wk, Wv, Wo, wqT);
  // 3. fused QKV projection + bias + RoPE (+ (1/8)*log2e fold into Q)
  k_gemm_qkv<<<dim3(24, 32), 256, 0, stream>>>(xb, wqT, bq, bk, bv, cosT, sinT, qb, kb, vb);
  // 4. causal flash attention (2-deep reg-staged prefetch, raw barriers)
  k_flash<<<dim3(45 * 32), 256, 0, stream>>>(qb, kb, vb, ctx, pO, pML);
  // 5. combine split halves (qt 19..31)
  k_combine<<<dim3(13 * 32), 256, 0, stream>>>(pO, pML, ctx);
  // 6. output projection (f32 out)
  k_gemm<<<dim3(8, 32), 256, 0, stream>>>(ctx, woT, bo, out, 4096, 1024, 1024);
}

// Round 17
// 133.905 us; speedup vs baseline: 2.1886x; 1.0134x over previous
//
#include <hip/hip_runtime.h>
#include <hip/hip_bf16.h>

#define B_  2
#define S_  2048
#define D_  1024
#define H_  16
#define DH_ 64

typedef __attribute__((ext_vector_type(8))) short bf16x8;
typedef __attribute__((ext_vector_type(4))) float f32x4;

__device__ __forceinline__ short f2bf(float f) {
  unsigned int u; __builtin_memcpy(&u, &f, 4);
  u = (u + 0x7FFFu + ((u >> 16) & 1u)) >> 16;
  return (short)u;
}
// packed f32x2 -> bf16x2 (RNE), lo = first arg
__device__ __forceinline__ unsigned cvtpk(float a, float b) {
  unsigned r;
  asm("v_cvt_pk_bf16_f32 %0, %1, %2" : "=v"(r) : "v"(a), "v"(b));
  return r;
}

#define GLOAD_LDS16(gp, lp) \
  __builtin_amdgcn_global_load_lds((const __attribute__((address_space(1))) void*)(gp), \
                                   (__attribute__((address_space(3))) void*)(lp), 16, 0, 0)

#define MFMA16(a, b, c) __builtin_amdgcn_mfma_f32_16x16x32_bf16(a, b, c, 0, 0, 0)

// lgkm-only barrier: LDS writes visible, in-flight global loads NOT drained.
#define RAW_BARRIER() do {                                   \
    asm volatile("s_waitcnt lgkmcnt(0)" ::: "memory");       \
    __builtin_amdgcn_s_barrier();                            \
    asm volatile("" ::: "memory");                           \
  } while (0)

union U8 { unsigned u[4]; bf16x8 v; };

// ---------------- f32 -> bf16 convert (x) + RoPE table (fused) ----------------
__global__ __launch_bounds__(256) void k_cvt_table(const float* __restrict__ in,
                                                   short* __restrict__ out,
                                                   float* __restrict__ cosT,
                                                   float* __restrict__ sinT) {
  int bid = blockIdx.x;
  if (bid < 4096) {                      // cvt: 4096 blocks x 256 thr x float4
    int i = bid * 256 + threadIdx.x;
    float4 v = ((const float4*)in)[i];
    short4 o; o.x = f2bf(v.x); o.y = f2bf(v.y); o.z = f2bf(v.z); o.w = f2bf(v.w);
    *(short4*)(out + (size_t)i * 4) = o;
  } else {                               // table: 256 blocks (S*32 entries)
    int i = (bid - 4096) * 256 + threadIdx.x;
    int s = i >> 5, d = i & 31;
    float invf = exp2f(-(float)d * (13.287712379549449f / 32.0f)); // 10000^(-d/32)
    float ang = (float)s * invf;
    cosT[i] = cosf(ang);
    sinT[i] = sinf(ang);
  }
}

// ---------------- 4 weights (f32 [K][N]) -> Wt (bf16 [N][K]), one launch ----------------
__global__ __launch_bounds__(256) void k_transpose4(const float* __restrict__ W0,
                                                    const float* __restrict__ W1,
                                                    const float* __restrict__ W2,
                                                    const float* __restrict__ W3,
                                                    short* __restrict__ WtBase) {
  __shared__ float tile[32][33];
  const float* W = (blockIdx.z == 0) ? W0 : (blockIdx.z == 1) ? W1 :
                   (blockIdx.z == 2) ? W2 : W3;
  short* Wt = WtBase + (size_t)blockIdx.z * D_ * D_;
  int tx = threadIdx.x, ty = threadIdx.y;
  int bx = blockIdx.x * 32, by = blockIdx.y * 32;
  #pragma unroll
  for (int i = 0; i < 32; i += 8)
    tile[ty + i][tx] = W[(size_t)(by + ty + i) * D_ + bx + tx];
  __syncthreads();
  #pragma unroll
  for (int i = 0; i < 32; i += 8)
    Wt[(size_t)(bx + ty + i) * D_ + by + tx] = f2bf(tile[tx][ty + i]);
}

// ---------------- fused QKV GEMM + bias + RoPE epilogue (XCD-swizzled grid) ----------------
__global__ __launch_bounds__(256) void k_gemm_qkv(const short* __restrict__ A,
                                                  const short* __restrict__ Bt,
                                                  const float* __restrict__ bq,
                                                  const float* __restrict__ bk,
                                                  const float* __restrict__ bv,
                                                  const float* __restrict__ cosT,
                                                  const float* __restrict__ sinT,
                                                  short* __restrict__ qb,
                                                  short* __restrict__ kb,
                                                  short* __restrict__ vb) {
  const int K = 1024;
  __shared__ __align__(16) short lA[128 * 32];
  __shared__ __align__(16) short lB[128 * 32];
  // XCD-bijective swizzle: 768 blocks (%8==0), chunk = 96 per XCD
  const int fid = blockIdx.y * 24 + blockIdx.x;
  const int swz = (fid & 7) * 96 + (fid >> 3);
  const int bxs = swz % 24, bys = swz / 24;
  const int tid = threadIdx.x;
  const int wid = tid >> 6, lane = tid & 63;
  const int brow = bys * 128, bcol = bxs * 128;
  const int wr = wid >> 1, wc = wid & 1;
  const int g = lane >> 4, c15 = lane & 15;
  const int sr = lane >> 2, scol = (lane & 3) * 8;
  f32x4 acc[4][4] = {};

  for (int kt = 0; kt < K; kt += 32) {
    __syncthreads();
    #pragma unroll
    for (int ch = 0; ch < 2; ++ch) {
      const short* ga = A + (size_t)(brow + ch * 64 + wid * 16 + sr) * K + kt + scol;
      const short* gb = Bt + (size_t)(bcol + ch * 64 + wid * 16 + sr) * K + kt + scol;
      GLOAD_LDS16(ga, &lA[(ch * 64 + wid * 16) * 32]);
      GLOAD_LDS16(gb, &lB[(ch * 64 + wid * 16) * 32]);
    }
    __syncthreads();
    bf16x8 af[4], bfr[4];
    #pragma unroll
    for (int mi = 0; mi < 4; ++mi)
      af[mi] = *(const bf16x8*)&lA[(wr * 64 + mi * 16 + c15) * 32 + g * 8];
    #pragma unroll
    for (int ni = 0; ni < 4; ++ni)
      bfr[ni] = *(const bf16x8*)&lB[(wc * 64 + ni * 16 + c15) * 32 + g * 8];
    #pragma unroll
    for (int mi = 0; mi < 4; ++mi)
      #pragma unroll
      for (int ni = 0; ni < 4; ++ni)
        acc[mi][ni] = MFMA16(af[mi], bfr[ni], acc[mi][ni]);
  }

  const int seg = bcol >> 10;                       // 0=q 1=k 2=v
  const float* bp = (seg == 0) ? bq : (seg == 1) ? bk : bv;
  short* dst = (seg == 0) ? qb : (seg == 1) ? kb : vb;
  const float alpha = (seg == 0) ? 0.18033688f : 1.0f;  // (1/8)*log2(e)
  const bool rope = (seg < 2);
  #pragma unroll
  for (int mi = 0; mi < 4; ++mi) {
    #pragma unroll
    for (int ni = 0; ni < 2; ++ni) {
      int col  = bcol + wc * 64 + ni * 16 + c15;
      int lcol = col & 1023;
      int d    = col & 63;                          // 0..31 (ni<2)
      float b1 = bp[lcol], b2 = bp[lcol + 32];
      #pragma unroll
      for (int r = 0; r < 4; ++r) {
        int row = brow + wr * 64 + mi * 16 + g * 4 + r;
        float x1 = (acc[mi][ni][r]     + b1) * alpha;
        float x2 = (acc[mi][ni + 2][r] + b2) * alpha;
        float o1 = x1, o2 = x2;
        if (rope) {
          int s = row & (S_ - 1);
          float co = cosT[s * 32 + d], si = sinT[s * 32 + d];
          o1 = x1 * co - x2 * si;
          o2 = x1 * si + x2 * co;
        }
        dst[(size_t)row * 1024 + lcol]      = f2bf(o1);
        dst[(size_t)row * 1024 + lcol + 32] = f2bf(o2);
      }
    }
  }
}

// ---------------- bf16 GEMM (Wo): C = A*Bt^T + bias(col), f32 out ----------------
__global__ __launch_bounds__(256) void k_gemm(const short* __restrict__ A,
                                              const short* __restrict__ Bt,
                                              const float* __restrict__ bias,
                                              float* __restrict__ out,
                                              int M, int N, int K) {
  __shared__ __align__(16) short lA[128 * 32];
  __shared__ __align__(16) short lB[128 * 32];
  // XCD-bijective swizzle: 256 blocks (%8==0), chunk = 32 per XCD
  const int fid = blockIdx.y * 8 + blockIdx.x;
  const int swz = (fid & 7) * 32 + (fid >> 3);
  const int bxs = swz % 8, bys = swz / 8;
  const int tid = threadIdx.x;
  const int wid = tid >> 6, lane = tid & 63;
  const int brow = bys * 128, bcol = bxs * 128;
  const int wr = wid >> 1, wc = wid & 1;
  const int g = lane >> 4, c15 = lane & 15;
  const int sr = lane >> 2, scol = (lane & 3) * 8;
  f32x4 acc[4][4] = {};

  for (int kt = 0; kt < K; kt += 32) {
    __syncthreads();
    #pragma unroll
    for (int ch = 0; ch < 2; ++ch) {
      const short* ga = A + (size_t)(brow + ch * 64 + wid * 16 + sr) * K + kt + scol;
      const short* gb = Bt + (size_t)(bcol + ch * 64 + wid * 16 + sr) * K + kt + scol;
      GLOAD_LDS16(ga, &lA[(ch * 64 + wid * 16) * 32]);
      GLOAD_LDS16(gb, &lB[(ch * 64 + wid * 16) * 32]);
    }
    __syncthreads();
    bf16x8 af[4], bfr[4];
    #pragma unroll
    for (int mi = 0; mi < 4; ++mi)
      af[mi] = *(const bf16x8*)&lA[(wr * 64 + mi * 16 + c15) * 32 + g * 8];
    #pragma unroll
    for (int ni = 0; ni < 4; ++ni)
      bfr[ni] = *(const bf16x8*)&lB[(wc * 64 + ni * 16 + c15) * 32 + g * 8];
    #pragma unroll
    for (int mi = 0; mi < 4; ++mi)
      #pragma unroll
      for (int ni = 0; ni < 4; ++ni)
        acc[mi][ni] = MFMA16(af[mi], bfr[ni], acc[mi][ni]);
  }

  #pragma unroll
  for (int mi = 0; mi < 4; ++mi) {
    #pragma unroll
    for (int ni = 0; ni < 4; ++ni) {
      int col = bcol + wc * 64 + ni * 16 + c15;
      float bv = bias[col];
      #pragma unroll
      for (int r = 0; r < 4; ++r) {
        int row = brow + wr * 64 + mi * 16 + g * 4 + r;
        out[(size_t)row * N + col] = acc[mi][ni][r] + bv;
      }
    }
  }
}

// ---- flash helpers ----
// softmax without denominator reduction: m update + rescale (o and lo4) + exp2.
// l is accumulated by the MFMA-ones trick in the PV phase (see FBODY).
__device__ __forceinline__ void softmax_m(f32x4 (&s)[4], float& m,
                                          f32x4 (&o)[4], f32x4& lo4, int g) {
  float pm = -1e30f;
  #pragma unroll
  for (int n = 0; n < 4; ++n)
    #pragma unroll
    for (int r = 0; r < 4; ++r) pm = fmaxf(pm, s[n][r]);
  pm = fmaxf(pm, __shfl_xor(pm, 16));
  pm = fmaxf(pm, __shfl_xor(pm, 32));
  if (!__all(pm <= m + 8.0f)) {   // defer-max THR=8 (log2 units)
    float nm = fmaxf(m, pm);
    float corr = exp2f(m - nm);
    m = nm;
    float cf[4];
    #pragma unroll
    for (int r = 0; r < 4; ++r) cf[r] = __shfl(corr, g * 4 + r);
    #pragma unroll
    for (int dblk = 0; dblk < 4; ++dblk)
      #pragma unroll
      for (int r = 0; r < 4; ++r) o[dblk][r] *= cf[r];
    #pragma unroll
    for (int r = 0; r < 4; ++r) lo4[r] *= cf[r];
  }
  #pragma unroll
  for (int n = 0; n < 4; ++n)
    #pragma unroll
    for (int r = 0; r < 4; ++r)
      s[n][r] = exp2f(s[n][r] - m);
}

__device__ __forceinline__ void build_pa(const f32x4 (&s)[4], U8 (&pa)[2],
                                         int g, int c15) {
  unsigned pk[4][2];
  #pragma unroll
  for (int n = 0; n < 4; ++n) {
    pk[n][0] = cvtpk(s[n][0], s[n][1]);
    pk[n][1] = cvtpk(s[n][2], s[n][3]);
  }
  #pragma unroll
  for (int kh = 0; kh < 2; ++kh) {
    #pragma unroll
    for (int widx = 0; widx < 4; ++widx) {
      int src = (2 * (g & 1) + (widx >> 1)) * 16 + c15;
      unsigned lo = __shfl(pk[2 * kh][widx & 1], src);
      unsigned hi = __shfl(pk[2 * kh + 1][widx & 1], src);
      pa[kh].u[widx] = (g & 2) ? hi : lo;
    }
  }
}

// ---------------- causal flash attention (R10 base + MFMA-ones denominator) ----------------
// 4 waves/block, wave owns 16 q-rows (qt*64 + w*16). KV tile 64, K+V double-buffered
// in LDS, reg-staged 2 tiles ahead; lgkm-only barriers. l computed via D = P*ones MFMA
// (lands per-row in O-layout -> no rs reduction, no epilogue l broadcast shfls).
// 45 scheds x 32 bh, KV-split for qt>=19.
__global__ __launch_bounds__(256, 4) void k_flash(const short* __restrict__ Qb,
                                                  const short* __restrict__ Kb,
                                                  const short* __restrict__ Vb,
                                                  short* __restrict__ Ctx,
                                                  float* __restrict__ pO,
                                                  float* __restrict__ pML) {
  __shared__ __align__(16) short Vt[2][64][72];  // V[kv][d] at Vt[d][kv^((d>>4)<<3)]
  __shared__ __align__(16) short Kl[2][4096];    // K[kv][d] at kv*64 + ((d>>3)^(kv&7))*8 + (d&7)
  const int bid = blockIdx.x;
  const int sched = bid >> 5, bh = bid & 31;
  int qt, t0, t1, sid = 0; bool split;
  if (sched < 19) { qt = 18 - sched; t0 = 0; t1 = qt; split = false; }
  else {
    int j = sched - 19; qt = 31 - (j >> 1);
    int h1 = (qt + 2) >> 1;                       // ceil((qt+1)/2)
    if ((j & 1) == 0) { t0 = h1; t1 = qt; }       // late half
    else              { t0 = 0;  t1 = h1 - 1; }   // early half
    split = true; sid = bh * 26 + j;
  }
  const int b   = bh >> 4, h = bh & 15;
  const int tid = threadIdx.x, w = tid >> 6, lane = tid & 63;
  const int g   = lane >> 4, c15 = lane & 15;
  const int qg0 = qt * 64 + w * 16;
  const int qabs = qg0 + c15;

  // Q fragments (B-operand of swapped QK^T)
  const short* qp = Qb + ((size_t)(b * S_ + qabs)) * D_ + h * DH_ + g * 8;
  bf16x8 qf0 = *(const bf16x8*)qp;
  bf16x8 qf1 = *(const bf16x8*)(qp + 32);

  // ones B-fragment for the denominator MFMA (bf16 1.0 = 0x3F80)
  bf16x8 onesv;
  #pragma unroll
  for (int j = 0; j < 8; ++j) onesv[j] = (short)0x3F80;

  // V staging: wave w stages d-slice [w*16, +16) for all 64 kv (lane = kv)
  const int vkv = lane;
  const int vd0 = w * 16;
  const int vcol = vkv ^ (w << 3);
  const short* vrow = Vb + (size_t)b * S_ * D_ + h * DH_ + vd0;

  // K staging addresses (reg-staged): thread covers kidx0, kidx1 (16B each)
  const short* kbase = Kb + (size_t)b * S_ * D_ + h * DH_;
  const int kidx0 = w * 128 + lane;
  const int kkv0 = kidx0 >> 3, kdb0 = (kidx0 & 7) ^ (kkv0 & 7);
  const int kidx1 = kidx0 + 64;
  const int kkv1 = kidx1 >> 3, kdb1 = (kidx1 & 7) ^ (kkv1 & 7);

  f32x4 o[4] = {};
  f32x4 lo4 = {};              // per-row denominator, O-layout (row = g*4+r)
  float m = -1e30f;

  // staging register sets: c = holds tile t+1 at top of body t; n = receives t+2
  bf16x8 kc0, kc1, vc0, vc1, kn0, kn1, vn0, vn1;

  // prologue: load+write tile t0, then issue loads for t0+1 into the hold set
  {
    const short* kb0 = kbase + (size_t)(t0 * 64) * D_;
    bf16x8 tk0 = *(const bf16x8*)(kb0 + (size_t)kkv0 * D_ + kdb0 * 8);
    bf16x8 tk1 = *(const bf16x8*)(kb0 + (size_t)kkv1 * D_ + kdb1 * 8);
    const short* vp = vrow + (size_t)(t0 * 64 + vkv) * D_;
    bf16x8 tv0 = *(const bf16x8*)vp;
    bf16x8 tv1 = *(const bf16x8*)(vp + 8);
    *(bf16x8*)&Kl[t0 & 1][kidx0 * 8] = tk0;
    *(bf16x8*)&Kl[t0 & 1][kidx1 * 8] = tk1;
    #pragma unroll
    for (int j = 0; j < 8; ++j) Vt[t0 & 1][vd0 + j][vcol] = tv0[j];
    #pragma unroll
    for (int j = 0; j < 8; ++j) Vt[t0 & 1][vd0 + 8 + j][vcol] = tv1[j];
    if (t0 + 1 <= t1) {
      const short* kb1 = kbase + (size_t)((t0 + 1) * 64) * D_;
      kc0 = *(const bf16x8*)(kb1 + (size_t)kkv0 * D_ + kdb0 * 8);
      kc1 = *(const bf16x8*)(kb1 + (size_t)kkv1 * D_ + kdb1 * 8);
      const short* vp1 = vrow + (size_t)((t0 + 1) * 64 + vkv) * D_;
      vc0 = *(const bf16x8*)vp1;
      vc1 = *(const bf16x8*)(vp1 + 8);
    }
  }
  RAW_BARRIER();   // lgkm only: t0+1 loads stay in flight

  // body: issue loads(T+2)->N; compute T; write C(=T+1)->LDS; raw barrier
#define FBODY(T, KC0, KC1, VC0, VC1, KN0, KN1, VN0, VN1) do {                   \
    const int kv0 = (T) * 64;                                                   \
    if ((T) + 2 <= t1) {                                                        \
      const short* kb2 = kbase + (size_t)(kv0 + 128) * D_;                      \
      KN0 = *(const bf16x8*)(kb2 + (size_t)kkv0 * D_ + kdb0 * 8);               \
      KN1 = *(const bf16x8*)(kb2 + (size_t)kkv1 * D_ + kdb1 * 8);               \
      const short* vp2 = vrow + (size_t)(kv0 + 128 + vkv) * D_;                 \
      VN0 = *(const bf16x8*)vp2;                                                \
      VN1 = *(const bf16x8*)(vp2 + 8);                                          \
    }                                                                           \
    if (kv0 <= qg0 + 15) {                                                      \
      const short* ks = &Kl[(T) & 1][0];                                        \
      f32x4 s[4] = {};                                                          \
      __builtin_amdgcn_s_setprio(1);                                            \
      _Pragma("unroll")                                                         \
      for (int n = 0; n < 4; ++n) {                                             \
        int krow = (n * 16 + c15) * 64;                                         \
        bf16x8 k0 = *(const bf16x8*)&ks[krow + ((g ^ (c15 & 7)) * 8)];          \
        bf16x8 k1 = *(const bf16x8*)&ks[krow + (((g + 4) ^ (c15 & 7)) * 8)];    \
        s[n] = MFMA16(k0, qf0, s[n]);                                           \
        s[n] = MFMA16(k1, qf1, s[n]);                                           \
      }                                                                         \
      __builtin_amdgcn_s_setprio(0);                                            \
      if (kv0 + 63 > qg0) {                                                     \
        _Pragma("unroll")                                                       \
        for (int n = 0; n < 4; ++n)                                             \
          _Pragma("unroll")                                                     \
          for (int r = 0; r < 4; ++r)                                           \
            if (kv0 + n * 16 + g * 4 + r > qabs) s[n][r] = -1e30f;              \
      }                                                                         \
      softmax_m(s, m, o, lo4, g);                                               \
      U8 pa[2];                                                                 \
      build_pa(s, pa, g, c15);                                                  \
      __builtin_amdgcn_s_setprio(1);                                            \
      _Pragma("unroll")                                                         \
      for (int kh = 0; kh < 2; ++kh)                                            \
        _Pragma("unroll")                                                       \
        for (int dblk = 0; dblk < 4; ++dblk) {                                  \
          bf16x8 vbf = *(const bf16x8*)&Vt[(T) & 1][dblk * 16 + c15]            \
                                         [kh * 32 + ((g ^ dblk) * 8)];          \
          o[dblk] = MFMA16(pa[kh].v, vbf, o[dblk]);                             \
        }                                                                       \
      lo4 = MFMA16(pa[0].v, onesv, lo4);                                        \
      lo4 = MFMA16(pa[1].v, onesv, lo4);                                        \
      __builtin_amdgcn_s_setprio(0);                                            \
    }                                                                           \
    if ((T) + 1 <= t1) {                                                        \
      *(bf16x8*)&Kl[((T) + 1) & 1][kidx0 * 8] = KC0;                            \
      *(bf16x8*)&Kl[((T) + 1) & 1][kidx1 * 8] = KC1;                            \
      _Pragma("unroll")                                                         \
      for (int j = 0; j < 8; ++j) Vt[((T) + 1) & 1][vd0 + j][vcol] = VC0[j];    \
      _Pragma("unroll")                                                         \
      for (int j = 0; j < 8; ++j) Vt[((T) + 1) & 1][vd0 + 8 + j][vcol] = VC1[j];\
      RAW_BARRIER();                                                            \
    }                                                                           \
  } while (0)

  for (int t = t0; t <= t1; ) {
    FBODY(t, kc0, kc1, vc0, vc1, kn0, kn1, vn0, vn1);
    ++t;
    if (t > t1) break;
    FBODY(t, kn0, kn1, vn0, vn1, kc0, kc1, vc0, vc1);
    ++t;
  }
#undef FBODY

  if (!split) {
    // ---- epilogue: normalize (l already per-row in-lane), store ctx ----
    float linv[4];
    #pragma unroll
    for (int r = 0; r < 4; ++r) linv[r] = 1.0f / lo4[r];
    #pragma unroll
    for (int dblk = 0; dblk < 4; ++dblk)
      #pragma unroll
      for (int r = 0; r < 4; ++r) {
        int q = qg0 + g * 4 + r;
        Ctx[((size_t)(b * S_ + q)) * D_ + h * DH_ + dblk * 16 + c15] = f2bf(o[dblk][r] * linv[r]);
      }
  } else {
    // ---- epilogue: raw partial O (f32) + per-row m,l ----
    float* po = pO + ((size_t)sid * 64 + w * 16) * 64;
    #pragma unroll
    for (int dblk = 0; dblk < 4; ++dblk)
      #pragma unroll
      for (int r = 0; r < 4; ++r)
        po[(g * 4 + r) * 64 + dblk * 16 + c15] = o[dblk][r];
    if (lane < 16) {   // lanes 0..15 (g=0, c15=lane): m is per-row q=c15
      pML[(size_t)sid * 128 + w * 16 + lane] = m;
    }
    if (c15 == 0) {    // lanes g*16: lo4[r] is l for row g*4+r
      #pragma unroll
      for (int r = 0; r < 4; ++r)
        pML[(size_t)sid * 128 + 64 + w * 16 + g * 4 + r] = lo4[r];
    }
  }
}

// ---------------- combine split halves: ctx rows for qt in [19,31] ----------------
__global__ __launch_bounds__(256) void k_combine(const float* __restrict__ pO,
                                                 const float* __restrict__ pML,
                                                 short* __restrict__ Ctx) {
  const int p = blockIdx.x;           // 13 qt x 32 bh
  const int qt = 19 + (p >> 5), bh = p & 31;
  const int b = bh >> 4, h = bh & 15;
  const int jb = (31 - qt) * 2;
  const int sidB = bh * 26 + jb;      // late half
  const int sidA = bh * 26 + jb + 1;  // early half
  const int q = threadIdx.x >> 2;
  const int d0 = (threadIdx.x & 3) * 16;
  float mA = pML[(size_t)sidA * 128 + q], lA = pML[(size_t)sidA * 128 + 64 + q];
  float mB = pML[(size_t)sidB * 128 + q], lB = pML[(size_t)sidB * 128 + 64 + q];
  float M = fmaxf(mA, mB);
  float wA = exp2f(mA - M), wB = exp2f(mB - M);
  float inv = 1.0f / (lA * wA + lB * wB);
  const float* oA = pO + ((size_t)sidA * 64 + q) * 64 + d0;
  const float* oB = pO + ((size_t)sidB * 64 + q) * 64 + d0;
  short* cp = Ctx + ((size_t)(b * S_ + qt * 64 + q)) * D_ + h * DH_ + d0;
  #pragma unroll
  for (int i = 0; i < 16; i += 4) {
    float4 a = *(const float4*)(oA + i);
    float4 c = *(const float4*)(oB + i);
    cp[i + 0] = f2bf((a.x * wA + c.x * wB) * inv);
    cp[i + 1] = f2bf((a.y * wA + c.y * wB) * inv);
    cp[i + 2] = f2bf((a.z * wA + c.z * wB) * inv);
    cp[i + 3] = f2bf((a.w * wA + c.w * wB) * inv);
  }
}

extern "C" void kernel_launch(void* const* d_in, const int* in_sizes, int n_in,
                              void* d_out, int out_size, void* d_ws, size_t ws_size,
                              hipStream_t stream) {
  (void)in_sizes; (void)n_in; (void)out_size; (void)ws_size;
  const float* x  = (const float*)d_in[0];
  const float* Wq = (const float*)d_in[1];
  const float* bq = (const float*)d_in[2];
  const float* Wk = (const float*)d_in[3];
  const float* bk = (const float*)d_in[4];
  const float* Wv = (const float*)d_in[5];
  const float* bv = (const float*)d_in[6];
  const float* Wo = (const float*)d_in[7];
  const float* bo = (const float*)d_in[8];
  float* out = (float*)d_out;
  char* ws = (char*)d_ws;

  const size_t MS = (size_t)B_ * S_;  // 4096
  short* xb  = (short*)(ws);                                  // 8 MB (pre-flash)
  short* wqT = (short*)(ws + (size_t)8 * 1024 * 1024);        // 2 MB each, contiguous
  short* wkT = wqT + (size_t)D_ * D_;
  short* wvT = wkT + (size_t)D_ * D_;
  short* woT = wvT + (size_t)D_ * D_;                         // needed till the end
  short* qb  = (short*)(ws + (size_t)16 * 1024 * 1024);       // 8 MB each
  short* kb  = qb + MS * D_;
  short* vb  = kb + MS * D_;
  short* ctx = vb + MS * D_;
  float* cosT = (float*)(ws + (size_t)48 * 1024 * 1024);      // 256 KB each
  float* sinT = cosT + (size_t)S_ * 32;
  // flash partials: pO aliases [0,14MB) (xb+wqT/wkT/wvT, dead after qkv GEMM);
  // 832 slots x 64 rows x 64 f32 = 13.3 MB. pML: 832 x 128 f32 = 426 KB.
  float* pO  = (float*)(ws);
  float* pML = (float*)(ws + (size_t)48 * 1024 * 1024 + 512 * 1024);

  // 1. x -> bf16 + rope table (fused)
  k_cvt_table<<<dim3(4096 + 256), 256, 0, stream>>>(x, xb, cosT, sinT);
  // 2. weights -> bf16 transposed (one launch; wqT..woT contiguous)
  k_transpose4<<<dim3(32, 32, 4), dim3(32, 8), 0, stream>>>(Wq, Wk, Wv, Wo, wqT);
  // 3. fused QKV projection + bias + RoPE (+ (1/8)*log2e fold into Q)
  k_gemm_qkv<<<dim3(24, 32), 256, 0, stream>>>(xb, wqT, bq, bk, bv, cosT, sinT, qb, kb, vb);
  // 4. causal flash attention (MFMA-ones denominator, 2-deep prefetch, raw barriers)
  k_flash<<<dim3(45 * 32), 256, 0, stream>>>(qb, kb, vb, ctx, pO, pML);
  // 5. combine split halves (qt 19..31)
  k_combine<<<dim3(13 * 32), 256, 0, stream>>>(pO, pML, ctx);
  // 6. output projection (f32 out)
  k_gemm<<<dim3(8, 32), 256, 0, stream>>>(ctx, woT, bo, out, 4096, 1024, 1024);
}